// Round 18
// baseline (225.579 us; speedup 1.0000x reference)
//
#include <hip/hip_runtime.h>
#include <stdint.h>

// ---- problem constants (from setup_inputs) ----
#define NIMG 16
#define AANCH 3
#define HH 256
#define WW 336
#define HWP (HH*WW)            // 86016
#define NUM (AANCH*HWP)        // 258048 anchors per image
#define TOTAL (NIMG*NUM)       // 4128768
#define PRE_K 2000
#define POST_K 1000
#define NMS_TH 0.7f
#define NEGV -1e30f
#define CAND_CAP 4096
#define ROWS 2048              // padded row count for top-2000 arrays
#define RWORDS 64              // 32-bit mask words per NMS row (64*32 = 2048 bits)
#define CHUNK 4096             // elements per k_compact block
#define CBLOCKS (NUM / CHUNK)  // 63 blocks per image
#define HPARTS 16              // histogram partials per image
#define HBINS 4096             // 12-bit key prefix bins
#define HCHUNK (NUM / HPARTS)  // 16128 elements per hist block

// ---- workspace layout (bytes) ----
#define WS_HIST 0u             // 16 * 16 * 4096 * 4  = 4194304 (partial histograms)
                               // region is DEAD after hist's fused binsel; aliased:
#define WS_COLT 0u             //   colT   16*32*64*8 = 262144   (written by k_mask)
#define WS_CBOX 262144u        //   cboxes 16*4096*16 = 1048576  (written by k_compact)
#define WS_CSCO 1310720u       //   cscores 16*4096*4 = 262144   (written by k_compact)
#define WS_CUT  4194304u       // 16 u32 cut keys; +64B: 16 u32 nA (count above cut bin)
#define WS_CNT  4194560u       // 16 u32 cntA; 16 u32 cntB; +128B: done[16] (NEVER zeroed)
#define WS_CAND 4194816u       // 16 * 4096 * 8       = 524288
#define WS_BOX  4719104u       // 16 * 2048 * 16      = 524288
#define WS_SCO  5243392u       // 16 * 2048 * 4       = 131072
#define WS_RMI  5374464u       // 16 * 64 * 4         = 4096
#define WS_MASK 5444096u       // 16 * 2048 * 64 * 4  = 8388608
// total ~13.8 MB

// monotonic float -> uint key (descending float == descending key)
__device__ __forceinline__ uint32_t fkey(float f){
    uint32_t b = __float_as_uint(f);
    return (b & 0x80000000u) ? ~b : (b | 0x80000000u);
}
__device__ __forceinline__ float keyf(uint32_t k){
    uint32_t b = (k & 0x80000000u) ? (k & 0x7FFFFFFFu) : ~k;
    return __uint_as_float(b);
}

// ---- per-block private LDS histogram -> global partials; LAST block per image
// runs the bin-selection reduction inline (no separate k_binsel launch).
// done[img] is never initialized: 16 consecutive atomic increments cover all
// residues mod 16 exactly once, so exactly one block sees (old&15)==15.
__global__ __launch_bounds__(1024) void k_hist(const float* __restrict__ obj,
                                               uint32_t* __restrict__ part,
                                               uint32_t* __restrict__ cnt,
                                               uint32_t* __restrict__ rminit,
                                               uint32_t* __restrict__ done,
                                               uint32_t* __restrict__ cut,
                                               uint32_t* __restrict__ nAout){
    int img = blockIdx.x >> 4;
    int blk = blockIdx.x & 15;
    int tid = threadIdx.x;
    if (blockIdx.x == 0){
        for (int i = tid; i < 32 + NIMG * RWORDS; i += 1024){
            if (i < 32) cnt[i] = 0u;             // cntA[16] + cntB[16]
            else        rminit[i - 32] = 0u;
        }
    }
    __shared__ uint32_t h[HBINS];
    __shared__ uint32_t winner;
    #pragma unroll
    for (int i = 0; i < HBINS / 1024; ++i) h[tid + i * 1024] = 0u;
    __syncthreads();
    const float* base = obj + (size_t)img * NUM + (size_t)blk * HCHUNK;
    for (int e = tid * 4; e < HCHUNK; e += 4096){
        float4 v = *(const float4*)(base + e);
        atomicAdd(&h[fkey(v.x) >> 20], 1u);
        atomicAdd(&h[fkey(v.y) >> 20], 1u);
        atomicAdd(&h[fkey(v.z) >> 20], 1u);
        atomicAdd(&h[fkey(v.w) >> 20], 1u);
    }
    __syncthreads();
    uint32_t* p = part + ((size_t)blockIdx.x) * HBINS;
    #pragma unroll
    for (int i = 0; i < HBINS / 1024; ++i) p[tid + i * 1024] = h[tid + i * 1024];
    __threadfence();                             // release partials device-wide
    __syncthreads();
    if (tid == 0){
        uint32_t tk = atomicAdd(&done[img], 1u);
        winner = ((tk & 15u) == 15u) ? 1u : 0u;
    }
    __syncthreads();
    if (!winner) return;
    __threadfence();                             // acquire other blocks' partials
    // ---- fused binsel: merge 16 partials, find crossing bin, emit cut + nA ----
    uint32_t* ss = h;                            // reuse LDS (dead after store)
    const uint32_t* pb = part + (size_t)img * HPARTS * HBINS;
    int bin0 = HBINS - 4 * (tid + 1);            // tid=0 covers the top 4 bins
    uint32_t c0 = 0, c1 = 0, c2 = 0, c3 = 0;
    for (int k = 0; k < HPARTS; ++k){
        const uint4 v = *(const uint4*)(pb + (size_t)k * HBINS + bin0);
        c0 += v.x; c1 += v.y; c2 += v.z; c3 += v.w;
    }
    uint32_t s = c0 + c1 + c2 + c3;
    uint32_t x = s;
    __syncthreads();
    ss[tid] = x; __syncthreads();
    for (int d = 1; d < 1024; d <<= 1){
        uint32_t y = (tid >= d) ? ss[tid - d] : 0u;
        __syncthreads();
        x += y; ss[tid] = x;
        __syncthreads();
    }
    uint32_t incl = x, excl = x - s;
    if (excl < PRE_K && incl >= PRE_K){
        uint32_t c = excl;
        uint32_t cc[4] = {c0, c1, c2, c3};
        for (int j = 3; j >= 0; --j){            // walk bins descending by value
            uint32_t cb = c;                     // count strictly above bin (bin0+j)
            c += cc[j];
            if (c >= PRE_K){
                cut[img] = ((uint32_t)(bin0 + j)) << 20;
                nAout[img] = cb;
                break;
            }
        }
    }
}

// decode helper: composite write + box decode + clip + score
__device__ __forceinline__ void emit_candidate(
        uint32_t key, uint32_t f, uint32_t pos, int img,
        const float* __restrict__ anchors, const float* __restrict__ breg,
        float imw, float imh,
        unsigned long long* __restrict__ cand,
        float4* __restrict__ cboxes, float* __restrict__ cscores){
    const float CLIPV = 4.135166556742356f;     // log(1000/16)
    // composite: [key:32][~f:18][slot:14] — order by (key desc, f asc); f unique
    cand[img * CAND_CAP + pos] = ((unsigned long long)key << 32)
        | ((unsigned long long)((~f) & 0x3FFFFu) << 14) | (unsigned long long)pos;
    float logit = keyf(key);
    float sc = 1.0f / (1.0f + expf(-logit));
    const float* an = anchors + ((size_t)img * NUM + f) * 4;
    float ax1 = an[0], ay1 = an[1], ax2 = an[2], ay2 = an[3];
    int a = (int)(f % AANCH); int hw = (int)(f / AANCH);
    size_t bbase = ((size_t)img * 12 + a * 4) * HWP + (size_t)hw;
    float dx = breg[bbase], dy = breg[bbase + HWP];
    float dw = breg[bbase + 2 * (size_t)HWP], dh = breg[bbase + 3 * (size_t)HWP];
    float aw = ax2 - ax1 + 1.0f, ah = ay2 - ay1 + 1.0f;
    float cx = ax1 + 0.5f * aw, cy = ay1 + 0.5f * ah;
    dw = fminf(dw, CLIPV); dh = fminf(dh, CLIPV);
    float pcx = dx * aw + cx, pcy = dy * ah + cy;
    float pw = expf(dw) * aw, ph = expf(dh) * ah;
    float x1 = pcx - 0.5f * pw, y1 = pcy - 0.5f * ph;
    float x2 = pcx + 0.5f * pw - 1.0f, y2 = pcy + 0.5f * ph - 1.0f;
    x1 = fminf(fmaxf(x1, 0.0f), imw - 1.0f);
    y1 = fminf(fmaxf(y1, 0.0f), imh - 1.0f);
    x2 = fminf(fmaxf(x2, 0.0f), imw - 1.0f);
    y2 = fminf(fmaxf(y2, 0.0f), imh - 1.0f);
    bool valid = ((x2 - x1 + 1.0f) >= 0.0f) && ((y2 - y1 + 1.0f) >= 0.0f);
    cboxes[img * CAND_CAP + pos] = make_float4(x1, y1, x2, y2);
    cscores[img * CAND_CAP + pos] = valid ? sc : -sc;   // sign bit = validity
}

// ---- compact into TWO segments: A (bins > cutbin) at [0,nA), B (cut bin) at [nAp,..) ----
__global__ __launch_bounds__(256) void k_compact(const float* __restrict__ obj,
                                                 const uint32_t* __restrict__ cut,
                                                 const uint32_t* __restrict__ nAarr,
                                                 uint32_t* __restrict__ cnt,
                                                 unsigned long long* __restrict__ cand,
                                                 const float* __restrict__ anchors,
                                                 const float* __restrict__ breg,
                                                 const int* __restrict__ pimh,
                                                 const int* __restrict__ pimw,
                                                 float4* __restrict__ cboxes,
                                                 float* __restrict__ cscores){
    int img   = blockIdx.x / CBLOCKS;
    int chunk = blockIdx.x - img * CBLOCKS;
    int base  = img * NUM + chunk * CHUNK;     // flat element base
    __shared__ uint32_t lcA, lcB, gbA, gbB;
    __shared__ uint2 lbuf[CHUNK];              // A from front, B from back (32 KB)
    if (threadIdx.x == 0){ lcA = 0u; lcB = 0u; }
    __syncthreads();
    uint32_t cutv = cut[img];
    uint32_t cutbin = cutv >> 20;
    float4 v[4];
    #pragma unroll
    for (int it = 0; it < 4; ++it)             // 4 independent loads in flight
        v[it] = *(const float4*)(obj + base + it * 1024 + (int)threadIdx.x * 4);
    #pragma unroll
    for (int it = 0; it < 4; ++it){
        int e = it * 1024 + (int)threadIdx.x * 4;
        float vv[4] = {v[it].x, v[it].y, v[it].z, v[it].w};
        #pragma unroll
        for (int q = 0; q < 4; ++q){
            uint32_t k = fkey(vv[q]);
            if (k >= cutv){
                int r = chunk * CHUNK + e + q;       // index within image (a,h,w flat)
                int a = r / HWP, hw = r - a * HWP;
                uint32_t f = (uint32_t)(hw * AANCH + a);  // permute_and_flatten index
                if ((k >> 20) > cutbin){
                    uint32_t p = atomicAdd(&lcA, 1u);
                    lbuf[p] = make_uint2(k, f);
                } else {
                    uint32_t p = atomicAdd(&lcB, 1u);
                    lbuf[CHUNK - 1 - p] = make_uint2(k, f);
                }
            }
        }
    }
    __syncthreads();
    if (threadIdx.x == 0){
        gbA = (lcA > 0u) ? atomicAdd(&cnt[img], lcA) : 0u;
        gbB = (lcB > 0u) ? atomicAdd(&cnt[16 + img], lcB) : 0u;
    }
    __syncthreads();
    uint32_t nA  = nAarr[img];
    uint32_t nAp = (nA + 1u) & ~1u;
    float imw = (float)(*pimw), imh = (float)(*pimh);
    uint32_t na = lcA, ga = gbA, nb = lcB, gb = gbB;
    for (uint32_t t = threadIdx.x; t < na; t += 256u){
        uint32_t pos = ga + t;                  // pos < nA <= CAND_CAP guaranteed
        uint2 kf = lbuf[t];
        emit_candidate(kf.x, kf.y, pos, img, anchors, breg, imw, imh,
                       cand, cboxes, cscores);
    }
    for (uint32_t t = threadIdx.x; t < nb; t += 256u){
        uint32_t pos = nAp + gb + t;
        if (pos < CAND_CAP){
            uint2 kf = lbuf[CHUNK - 1 - t];
            emit_candidate(kf.x, kf.y, pos, img, anchors, breg, imw, imh,
                           cand, cboxes, cscores);
        }
    }
}

// ---- segmented O(n^2) rank: A scans A only, B scans B only (rank base = nA) ----
__global__ __launch_bounds__(256) void k_rank(
        const unsigned long long* __restrict__ cand, const uint32_t* __restrict__ cnt,
        const uint32_t* __restrict__ nAarr,
        const float4* __restrict__ cboxes, const float* __restrict__ cscores,
        float4* __restrict__ boxes_s, float* __restrict__ scores_s,
        uint32_t* __restrict__ rminit){
    int img = blockIdx.x >> 4;
    int b   = blockIdx.x & 15;
    int tid = threadIdx.x;
    int e   = b * 256 + tid;
    uint32_t nA   = nAarr[img];
    uint32_t nAp  = (nA + 1u) & ~1u;
    uint32_t nB   = min(cnt[16 + img], (uint32_t)CAND_CAP - nAp);
    uint32_t end  = nAp + nB;
    uint32_t endp = (end + 1u) & ~1u;
    const unsigned long long* cp = cand + img * CAND_CAP;
    __shared__ alignas(16) unsigned long long tile[CAND_CAP];
    for (int i = tid; i < (int)endp; i += 256){
        bool v = (i < (int)nA) || (i >= (int)nAp && i < (int)end);
        tile[i] = v ? cp[i] : 0ull;             // zero fillers never outrank
    }
    __syncthreads();
    bool inA = e < (int)nA;
    bool inB = (e >= (int)nAp) && (e < (int)end);
    bool validE = inA || inB;
    unsigned long long mine = validE ? tile[e] : ~0ull;
    int s0 = inA ? 0 : (inB ? (int)(nAp >> 1) : 0);
    int s1 = inA ? (int)(nAp >> 1) : (inB ? (int)(endp >> 1) : 0);
    int rank = inB ? (int)nA : 0;
    const ulonglong2* tile2 = (const ulonglong2*)tile;
    #pragma unroll 8
    for (int i = s0; i < s1; ++i){
        ulonglong2 p = tile2[i];                // broadcast within segment waves
        rank += (p.x > mine) ? 1 : 0;
        rank += (p.y > mine) ? 1 : 0;
    }
    if (validE && rank < PRE_K){
        float4 bx = cboxes[img * CAND_CAP + e];   // slot == e: coalesced gather
        float s   = cscores[img * CAND_CAP + e];
        boxes_s[img * ROWS + rank] = bx;
        scores_s[img * ROWS + rank] = fabsf(s);
        if (s < 0.0f) atomicOr(&rminit[img * RWORDS + (rank >> 5)], 1u << (rank & 31));
    }
}

// ---- build upper-triangle IoU>thresh bitmask rows + transposed diag blocks ----
// k_diag merged: waves gw<32 also emit colT for their 64x64 diagonal block
// (boxes/areas already staged). Staging extended to ROWS=2048; garbage rows
// >=2000 only influence bits k_scan pre-masks as removed (same as before).
__global__ __launch_bounds__(1024) void k_mask(const float4* __restrict__ boxes_s,
                                               uint32_t* __restrict__ mask,
                                               unsigned long long* __restrict__ colT){
    int img = blockIdx.x >> 4;                 // 16 blocks per image
    int rc  = blockIdx.x & 15;
    int tid = threadIdx.x;
    int lane = tid & 63;
    int wv = tid >> 6;                         // 16 waves per block
    int gw = rc * 16 + wv;                     // 0..255 wave slot within image
    __shared__ float4 B[ROWS];
    __shared__ float  AR[ROWS];
    const float4* bp = boxes_s + img * ROWS;
    for (int t = tid; t < ROWS; t += 1024){
        float4 b = bp[t]; B[t] = b;
        AR[t] = (b.z - b.x + 1.0f) * (b.w - b.y + 1.0f);
    }
    __syncthreads();
    if (gw < 32){                              // diag block gw: lane = column j
        int j = lane;
        float4 bj = B[gw * 64 + j]; float aj = AR[gw * 64 + j];
        unsigned long long col = 0ull;
        #pragma unroll 8
        for (int i = 0; i < 64; ++i){
            float4 bi = B[gw * 64 + i]; float ai = AR[gw * 64 + i];
            float xx1 = fmaxf(bi.x, bj.x), yy1 = fmaxf(bi.y, bj.y);
            float xx2 = fminf(bi.z, bj.z), yy2 = fminf(bi.w, bj.w);
            float iw = fmaxf(xx2 - xx1 + 1.0f, 0.0f);
            float ih = fmaxf(yy2 - yy1 + 1.0f, 0.0f);
            float inter = iw * ih;
            bool pred = (i < j) && (inter > NMS_TH * (ai + aj - inter));
            col |= pred ? (1ull << i) : 0ull;
        }
        colT[(size_t)(img * 32 + gw) * 64 + j] = col;
    }
    uint32_t* M = mask + (size_t)img * ROWS * RWORDS;
    for (int i = gw; i < PRE_K; i += 256){
        float4 bi = B[i];                      // same address across wave: broadcast
        float ai = AR[i];
        unsigned long long* Mrow = (unsigned long long*)(M + (size_t)i * RWORDS);
        for (int jb = (i >> 6); jb < 32; ++jb){
            int j = (jb << 6) + lane;
            bool pred = false;
            if (j > i && j < PRE_K){
                float4 bj = B[j];
                float xx1 = fmaxf(bi.x, bj.x), yy1 = fmaxf(bi.y, bj.y);
                float xx2 = fminf(bi.z, bj.z), yy2 = fminf(bi.w, bj.w);
                float iw = fmaxf(xx2 - xx1 + 1.0f, 0.0f);
                float ih = fmaxf(yy2 - yy1 + 1.0f, 0.0f);
                float inter = iw * ih;
                pred = inter > NMS_TH * (ai + AR[j] - inter);
            }
            unsigned long long bm = __ballot(pred);
            if (lane == 0) Mrow[jb] = bm;
        }
    }
}

// ---- blocked greedy NMS scan, 4-wave distributed apply + direct output ----
__global__ __launch_bounds__(256) void k_scan(const uint32_t* __restrict__ mask,
                                              const unsigned long long* __restrict__ colT,
                                              const uint32_t* __restrict__ rminit,
                                              const float4* __restrict__ boxes_s,
                                              const float* __restrict__ scores_s,
                                              float* __restrict__ out){
    int img = blockIdx.x;
    int tid = threadIdx.x;
    int lane = tid & 63;
    int wv = tid >> 6;
    const uint32_t* M = mask + (size_t)img * ROWS * RWORDS;
    const unsigned long long* CT = colT + (size_t)img * 32 * 64;
    __shared__ uint32_t S[POST_K];
    __shared__ uint32_t acc_lds[4][64];
    __shared__ unsigned long long keep_lds;

    uint32_t rm = 0u;
    if (wv == 0){
        rm = rminit[img * RWORDS + lane];
        if (lane == 62) rm |= 0xFFFF0000u;      // boxes 2000..2015
        if (lane == 63) rm  = 0xFFFFFFFFu;      // boxes 2016..2047
    }
    unsigned long long colA = 0ull, colB = 0ull, rmb_sav = 0ull;
    uint32_t rowsA[16], rowsB[16];

#define PRELOAD(B, ROWSX)                                                       \
    {                                                                           \
        const uint32_t* Mb = M + (size_t)((B) * 64 + wv * 16) * RWORDS + lane;  \
        _Pragma("unroll")                                                       \
        for (int r = 0; r < 16; ++r) ROWSX[r] = Mb[(size_t)r * RWORDS];         \
    }
#define FIXED_POINT(B, COLX)                                                    \
    {                                                                           \
        uint32_t lo = __shfl(rm, 2 * (B)), hi = __shfl(rm, 2 * (B) + 1);        \
        unsigned long long inc = ((unsigned long long)hi << 32)                 \
                               | (unsigned long long)lo;                        \
        bool alivej = ((inc >> lane) & 1ull) == 0ull;                           \
        unsigned long long keep = ~inc;                                         \
        for (int it = 0; it < 66; ++it){                                        \
            bool ok = alivej && ((COLX & keep) == 0ull);                        \
            unsigned long long nk = __ballot(ok);                              \
            if (nk == keep) break;                                              \
            keep = nk;                                                          \
        }                                                                       \
        if (lane == 0) keep_lds = keep;                                         \
        rmb_sav = ~keep;                                                        \
    }
#define APPLY(ROWSX)                                                            \
    {                                                                           \
        unsigned long long kp = keep_lds;                                       \
        uint32_t acc = 0u;                                                      \
        _Pragma("unroll")                                                       \
        for (int r = 0; r < 16; ++r)                                            \
            acc |= ((kp >> (wv * 16 + r)) & 1ull) ? ROWSX[r] : 0u;              \
        acc_lds[wv][lane] = acc;                                                \
    }
#define FINISH(B)                                                               \
    {                                                                           \
        uint32_t acc = acc_lds[0][lane] | acc_lds[1][lane]                      \
                     | acc_lds[2][lane] | acc_lds[3][lane];                     \
        rm |= (lane >= 2 * (B)) ? acc : 0u;                                     \
        if (lane == 2 * (B))     rm = (uint32_t)rmb_sav;                        \
        if (lane == 2 * (B) + 1) rm = (uint32_t)(rmb_sav >> 32);                \
    }

    // prologue: block 0 rows + col
    PRELOAD(0, rowsA);
    if (wv == 0) colA = CT[lane];

    #pragma unroll 1
    for (int b = 0; b < 32; b += 2){
        PRELOAD(b + 1, rowsB);
        if (wv == 0){
            colB = CT[(size_t)(b + 1) * 64 + lane];
            FIXED_POINT(b, colA);
        }
        __syncthreads();                        // keep_lds visible
        APPLY(rowsA);
        __syncthreads();                        // acc_lds visible
        if (wv == 0) FINISH(b);
        if (b + 2 < 32){
            PRELOAD(b + 2, rowsA);
            if (wv == 0) colA = CT[(size_t)(b + 2) * 64 + lane];
        }
        if (wv == 0) FIXED_POINT(b + 1, colB);
        __syncthreads();
        APPLY(rowsB);
        __syncthreads();
        if (wv == 0) FINISH(b + 1);
    }
#undef PRELOAD
#undef FIXED_POINT
#undef APPLY
#undef FINISH

    if (wv == 0){
        // kept = ~removed within [0, PRE_K)
        uint32_t inr = (lane < 62) ? 0xFFFFFFFFu : (lane == 62 ? 0x0000FFFFu : 0u);
        uint32_t kw = (~rm) & inr;
        uint32_t sw = rm & inr;
        uint32_t kc = __popc(kw);
        uint32_t x = kc;
        for (int d = 1; d < 64; d <<= 1){ uint32_t y = __shfl_up(x, d); if (lane >= d) x += y; }
        uint32_t kexcl = x - kc;
        uint32_t ktot = __shfl(x, 63);
        uint32_t m = kw; uint32_t r = 0;
        while (m){
            int bb = __ffs(m) - 1;
            uint32_t slot = kexcl + r;
            if (slot < POST_K) S[slot] = (uint32_t)(lane * 32 + bb) | 0x80000000u;
            m &= m - 1; ++r;
        }
        if (ktot < POST_K){   // pad with suppressed positions in index order
            uint32_t sc2 = __popc(sw);
            uint32_t x2 = sc2;
            for (int d = 1; d < 64; d <<= 1){ uint32_t y = __shfl_up(x2, d); if (lane >= d) x2 += y; }
            uint32_t sexcl = x2 - sc2;
            uint32_t m2 = sw; uint32_t r2 = 0;
            while (m2){
                int bb = __ffs(m2) - 1;
                uint32_t slot = ktot + sexcl + r2;
                if (slot >= ktot && slot < POST_K) S[slot] = (uint32_t)(lane * 32 + bb);
                m2 &= m2 - 1; ++r2;
            }
        }
    }
    __syncthreads();
    // direct output write: [1000, 5] rows for this image, 256 threads
    const float4* bp = boxes_s + img * ROWS;
    const float* sp = scores_s + img * ROWS;
    float* o = out + (size_t)img * POST_K * 5;
    for (int s = tid; s < POST_K; s += 256){
        uint32_t v = S[s];
        uint32_t pos = v & 0x7FFFFFFFu;
        bool kept = (v >> 31) != 0;
        float4 bx = bp[pos];
        float sc = kept ? sp[pos] : NEGV;
        float* oo = o + s * 5;
        oo[0] = bx.x; oo[1] = bx.y; oo[2] = bx.z; oo[3] = bx.w; oo[4] = sc;
    }
}

extern "C" void kernel_launch(void* const* d_in, const int* in_sizes, int n_in,
                              void* d_out, int out_size, void* d_ws, size_t ws_size,
                              hipStream_t stream) {
    const float* anchors = (const float*)d_in[0];
    const float* obj     = (const float*)d_in[1];
    const float* breg    = (const float*)d_in[2];
    const int*   pimh    = (const int*)d_in[3];
    const int*   pimw    = (const int*)d_in[4];
    float* out = (float*)d_out;
    uint8_t* ws = (uint8_t*)d_ws;

    uint32_t*           part     = (uint32_t*)(ws + WS_HIST);
    unsigned long long* colT     = (unsigned long long*)(ws + WS_COLT);  // alias, post-hist
    float4*             cboxes   = (float4*)(ws + WS_CBOX);              // alias, post-hist
    float*              cscores  = (float*)(ws + WS_CSCO);               // alias, post-hist
    uint32_t*           cut      = (uint32_t*)(ws + WS_CUT);
    uint32_t*           nAarr    = (uint32_t*)(ws + WS_CUT + 64);
    uint32_t*           cnt      = (uint32_t*)(ws + WS_CNT);             // cntA[16], cntB[16]
    uint32_t*           done     = (uint32_t*)(ws + WS_CNT + 128);       // NEVER zeroed (mod-16)
    unsigned long long* cand     = (unsigned long long*)(ws + WS_CAND);
    float4*             boxes_s  = (float4*)(ws + WS_BOX);
    float*              scores_s = (float*)(ws + WS_SCO);
    uint32_t*           rminit   = (uint32_t*)(ws + WS_RMI);
    uint32_t*           mask     = (uint32_t*)(ws + WS_MASK);

    k_hist<<<NIMG * HPARTS, 1024, 0, stream>>>(obj, part, cnt, rminit, done, cut, nAarr);
    k_compact<<<NIMG * CBLOCKS, 256, 0, stream>>>(obj, cut, nAarr, cnt, cand,
                                                  anchors, breg, pimh, pimw,
                                                  cboxes, cscores);
    k_rank<<<NIMG * 16, 256, 0, stream>>>(cand, cnt, nAarr, cboxes, cscores,
                                          boxes_s, scores_s, rminit);
    k_mask<<<NIMG * 16, 1024, 0, stream>>>(boxes_s, mask, colT);
    k_scan<<<NIMG, 256, 0, stream>>>(mask, colT, rminit, boxes_s, scores_s, out);
}

// Round 19
// 138.795 us; speedup vs baseline: 1.6253x; 1.6253x over previous
//
#include <hip/hip_runtime.h>
#include <stdint.h>

// ---- problem constants (from setup_inputs) ----
#define NIMG 16
#define AANCH 3
#define HH 256
#define WW 336
#define HWP (HH*WW)            // 86016
#define NUM (AANCH*HWP)        // 258048 anchors per image
#define TOTAL (NIMG*NUM)       // 4128768
#define PRE_K 2000
#define POST_K 1000
#define NMS_TH 0.7f
#define NEGV -1e30f
#define CAND_CAP 4096
#define ROWS 2048              // padded row count for top-2000 arrays
#define RWORDS 64              // 32-bit mask words per NMS row (64*32 = 2048 bits)
#define CHUNK 4096             // elements per k_compact block
#define CBLOCKS (NUM / CHUNK)  // 63 blocks per image
#define HPARTS 16              // histogram partials per image
#define HBINS 4096             // 12-bit key prefix bins
#define HCHUNK (NUM / HPARTS)  // 16128 elements per hist block

// ---- workspace layout (bytes) ----
#define WS_HIST 0u             // 16 * 16 * 4096 * 4  = 4194304 (partial histograms)
                               // region is DEAD after k_binsel; aliased below:
#define WS_COLT 0u             //   colT   16*32*64*8 = 262144   (written by k_mask)
#define WS_CBOX 262144u        //   cboxes 16*4096*16 = 1048576  (written by k_compact)
#define WS_CSCO 1310720u       //   cscores 16*4096*4 = 262144   (written by k_compact)
#define WS_CUT  4194304u       // 16 u32 cut keys; +64B: 16 u32 nA (count above cut bin)
#define WS_CNT  4194560u       // 16 u32 cntA; 16 u32 cntB
#define WS_CAND 4194816u       // 16 * 4096 * 8       = 524288
#define WS_BOX  4719104u       // 16 * 2048 * 16      = 524288
#define WS_SCO  5243392u       // 16 * 2048 * 4       = 131072
#define WS_RMI  5374464u       // 16 * 64 * 4         = 4096
#define WS_MASK 5444096u       // 16 * 2048 * 64 * 4  = 8388608
// total ~13.8 MB

// monotonic float -> uint key (descending float == descending key)
__device__ __forceinline__ uint32_t fkey(float f){
    uint32_t b = __float_as_uint(f);
    return (b & 0x80000000u) ? ~b : (b | 0x80000000u);
}
__device__ __forceinline__ float keyf(uint32_t k){
    uint32_t b = (k & 0x80000000u) ? (k & 0x7FFFFFFFu) : ~k;
    return __uint_as_float(b);
}

// ---- per-block private LDS histogram -> global partials (no global atomics) ----
// Also zeroes cntA/cntB + rminit (block 0). NOTE: cross-XCD reduction lives in
// the separate k_binsel launch — fusing it here requires __threadfence(), which
// forces L2 writeback across 8 non-coherent XCDs and cost ~95us (R17 lesson).
__global__ __launch_bounds__(1024) void k_hist(const float* __restrict__ obj,
                                               uint32_t* __restrict__ part,
                                               uint32_t* __restrict__ cnt,
                                               uint32_t* __restrict__ rminit){
    int img = blockIdx.x >> 4;
    int blk = blockIdx.x & 15;
    int tid = threadIdx.x;
    if (blockIdx.x == 0){
        for (int i = tid; i < 32 + NIMG * RWORDS; i += 1024){
            if (i < 32) cnt[i] = 0u;             // cntA[16] + cntB[16]
            else        rminit[i - 32] = 0u;
        }
    }
    __shared__ uint32_t h[HBINS];
    #pragma unroll
    for (int i = 0; i < HBINS / 1024; ++i) h[tid + i * 1024] = 0u;
    __syncthreads();
    const float* base = obj + (size_t)img * NUM + (size_t)blk * HCHUNK;
    for (int e = tid * 4; e < HCHUNK; e += 4096){
        float4 v = *(const float4*)(base + e);
        atomicAdd(&h[fkey(v.x) >> 20], 1u);
        atomicAdd(&h[fkey(v.y) >> 20], 1u);
        atomicAdd(&h[fkey(v.z) >> 20], 1u);
        atomicAdd(&h[fkey(v.w) >> 20], 1u);
    }
    __syncthreads();
    uint32_t* p = part + ((size_t)blockIdx.x) * HBINS;
    #pragma unroll
    for (int i = 0; i < HBINS / 1024; ++i) p[tid + i * 1024] = h[tid + i * 1024];
}

// ---- merge partials, find crossing bin; emit cut key AND nA (count above bin) ----
__global__ __launch_bounds__(1024) void k_binsel(const uint32_t* __restrict__ part,
                                                 uint32_t* __restrict__ cut,
                                                 uint32_t* __restrict__ nAout){
    int img = blockIdx.x, tid = threadIdx.x;
    const uint32_t* pb = part + (size_t)img * HPARTS * HBINS;
    int bin0 = HBINS - 4 * (tid + 1);           // tid=0 covers the top 4 bins
    uint32_t c0 = 0, c1 = 0, c2 = 0, c3 = 0;
    for (int k = 0; k < HPARTS; ++k){
        const uint4 v = *(const uint4*)(pb + (size_t)k * HBINS + bin0);
        c0 += v.x; c1 += v.y; c2 += v.z; c3 += v.w;
    }
    uint32_t s = c0 + c1 + c2 + c3;
    __shared__ uint32_t ss[1024];
    uint32_t x = s;
    ss[tid] = x; __syncthreads();
    for (int d = 1; d < 1024; d <<= 1){
        uint32_t y = (tid >= d) ? ss[tid - d] : 0u;
        __syncthreads();
        x += y; ss[tid] = x;
        __syncthreads();
    }
    uint32_t incl = x, excl = x - s;
    if (excl < PRE_K && incl >= PRE_K){
        uint32_t c = excl;
        uint32_t cc[4] = {c0, c1, c2, c3};
        for (int j = 3; j >= 0; --j){            // walk bins descending by value
            uint32_t cb = c;                     // count strictly above bin (bin0+j)
            c += cc[j];
            if (c >= PRE_K){
                cut[img] = ((uint32_t)(bin0 + j)) << 20;
                nAout[img] = cb;
                break;
            }
        }
    }
}

// decode helper: composite write + box decode + clip + score
__device__ __forceinline__ void emit_candidate(
        uint32_t key, uint32_t f, uint32_t pos, int img,
        const float* __restrict__ anchors, const float* __restrict__ breg,
        float imw, float imh,
        unsigned long long* __restrict__ cand,
        float4* __restrict__ cboxes, float* __restrict__ cscores){
    const float CLIPV = 4.135166556742356f;     // log(1000/16)
    // composite: [key:32][~f:18][slot:14] — order by (key desc, f asc); f unique
    cand[img * CAND_CAP + pos] = ((unsigned long long)key << 32)
        | ((unsigned long long)((~f) & 0x3FFFFu) << 14) | (unsigned long long)pos;
    float logit = keyf(key);
    float sc = 1.0f / (1.0f + expf(-logit));
    const float* an = anchors + ((size_t)img * NUM + f) * 4;
    float ax1 = an[0], ay1 = an[1], ax2 = an[2], ay2 = an[3];
    int a = (int)(f % AANCH); int hw = (int)(f / AANCH);
    size_t bbase = ((size_t)img * 12 + a * 4) * HWP + (size_t)hw;
    float dx = breg[bbase], dy = breg[bbase + HWP];
    float dw = breg[bbase + 2 * (size_t)HWP], dh = breg[bbase + 3 * (size_t)HWP];
    float aw = ax2 - ax1 + 1.0f, ah = ay2 - ay1 + 1.0f;
    float cx = ax1 + 0.5f * aw, cy = ay1 + 0.5f * ah;
    dw = fminf(dw, CLIPV); dh = fminf(dh, CLIPV);
    float pcx = dx * aw + cx, pcy = dy * ah + cy;
    float pw = expf(dw) * aw, ph = expf(dh) * ah;
    float x1 = pcx - 0.5f * pw, y1 = pcy - 0.5f * ph;
    float x2 = pcx + 0.5f * pw - 1.0f, y2 = pcy + 0.5f * ph - 1.0f;
    x1 = fminf(fmaxf(x1, 0.0f), imw - 1.0f);
    y1 = fminf(fmaxf(y1, 0.0f), imh - 1.0f);
    x2 = fminf(fmaxf(x2, 0.0f), imw - 1.0f);
    y2 = fminf(fmaxf(y2, 0.0f), imh - 1.0f);
    bool valid = ((x2 - x1 + 1.0f) >= 0.0f) && ((y2 - y1 + 1.0f) >= 0.0f);
    cboxes[img * CAND_CAP + pos] = make_float4(x1, y1, x2, y2);
    cscores[img * CAND_CAP + pos] = valid ? sc : -sc;   // sign bit = validity
}

// ---- compact into TWO segments: A (bins > cutbin) at [0,nA), B (cut bin) at [nAp,..) ----
__global__ __launch_bounds__(256) void k_compact(const float* __restrict__ obj,
                                                 const uint32_t* __restrict__ cut,
                                                 const uint32_t* __restrict__ nAarr,
                                                 uint32_t* __restrict__ cnt,
                                                 unsigned long long* __restrict__ cand,
                                                 const float* __restrict__ anchors,
                                                 const float* __restrict__ breg,
                                                 const int* __restrict__ pimh,
                                                 const int* __restrict__ pimw,
                                                 float4* __restrict__ cboxes,
                                                 float* __restrict__ cscores){
    int img   = blockIdx.x / CBLOCKS;
    int chunk = blockIdx.x - img * CBLOCKS;
    int base  = img * NUM + chunk * CHUNK;     // flat element base
    __shared__ uint32_t lcA, lcB, gbA, gbB;
    __shared__ uint2 lbuf[CHUNK];              // A from front, B from back (32 KB)
    if (threadIdx.x == 0){ lcA = 0u; lcB = 0u; }
    __syncthreads();
    uint32_t cutv = cut[img];
    uint32_t cutbin = cutv >> 20;
    float4 v[4];
    #pragma unroll
    for (int it = 0; it < 4; ++it)             // 4 independent loads in flight
        v[it] = *(const float4*)(obj + base + it * 1024 + (int)threadIdx.x * 4);
    #pragma unroll
    for (int it = 0; it < 4; ++it){
        int e = it * 1024 + (int)threadIdx.x * 4;
        float vv[4] = {v[it].x, v[it].y, v[it].z, v[it].w};
        #pragma unroll
        for (int q = 0; q < 4; ++q){
            uint32_t k = fkey(vv[q]);
            if (k >= cutv){
                int r = chunk * CHUNK + e + q;       // index within image (a,h,w flat)
                int a = r / HWP, hw = r - a * HWP;
                uint32_t f = (uint32_t)(hw * AANCH + a);  // permute_and_flatten index
                if ((k >> 20) > cutbin){
                    uint32_t p = atomicAdd(&lcA, 1u);
                    lbuf[p] = make_uint2(k, f);
                } else {
                    uint32_t p = atomicAdd(&lcB, 1u);
                    lbuf[CHUNK - 1 - p] = make_uint2(k, f);
                }
            }
        }
    }
    __syncthreads();
    if (threadIdx.x == 0){
        gbA = (lcA > 0u) ? atomicAdd(&cnt[img], lcA) : 0u;
        gbB = (lcB > 0u) ? atomicAdd(&cnt[16 + img], lcB) : 0u;
    }
    __syncthreads();
    uint32_t nA  = nAarr[img];
    uint32_t nAp = (nA + 1u) & ~1u;
    float imw = (float)(*pimw), imh = (float)(*pimh);
    uint32_t na = lcA, ga = gbA, nb = lcB, gb = gbB;
    for (uint32_t t = threadIdx.x; t < na; t += 256u){
        uint32_t pos = ga + t;                  // pos < nA <= CAND_CAP guaranteed
        uint2 kf = lbuf[t];
        emit_candidate(kf.x, kf.y, pos, img, anchors, breg, imw, imh,
                       cand, cboxes, cscores);
    }
    for (uint32_t t = threadIdx.x; t < nb; t += 256u){
        uint32_t pos = nAp + gb + t;
        if (pos < CAND_CAP){
            uint2 kf = lbuf[CHUNK - 1 - t];
            emit_candidate(kf.x, kf.y, pos, img, anchors, breg, imw, imh,
                           cand, cboxes, cscores);
        }
    }
}

// ---- segmented O(n^2) rank: A scans A only, B scans B only (rank base = nA) ----
__global__ __launch_bounds__(256) void k_rank(
        const unsigned long long* __restrict__ cand, const uint32_t* __restrict__ cnt,
        const uint32_t* __restrict__ nAarr,
        const float4* __restrict__ cboxes, const float* __restrict__ cscores,
        float4* __restrict__ boxes_s, float* __restrict__ scores_s,
        uint32_t* __restrict__ rminit){
    int img = blockIdx.x >> 4;
    int b   = blockIdx.x & 15;
    int tid = threadIdx.x;
    int e   = b * 256 + tid;
    uint32_t nA   = nAarr[img];
    uint32_t nAp  = (nA + 1u) & ~1u;
    uint32_t nB   = min(cnt[16 + img], (uint32_t)CAND_CAP - nAp);
    uint32_t end  = nAp + nB;
    uint32_t endp = (end + 1u) & ~1u;
    const unsigned long long* cp = cand + img * CAND_CAP;
    __shared__ alignas(16) unsigned long long tile[CAND_CAP];
    for (int i = tid; i < (int)endp; i += 256){
        bool v = (i < (int)nA) || (i >= (int)nAp && i < (int)end);
        tile[i] = v ? cp[i] : 0ull;             // zero fillers never outrank
    }
    __syncthreads();
    bool inA = e < (int)nA;
    bool inB = (e >= (int)nAp) && (e < (int)end);
    bool validE = inA || inB;
    unsigned long long mine = validE ? tile[e] : ~0ull;
    int s0 = inA ? 0 : (inB ? (int)(nAp >> 1) : 0);
    int s1 = inA ? (int)(nAp >> 1) : (inB ? (int)(endp >> 1) : 0);
    int rank = inB ? (int)nA : 0;
    const ulonglong2* tile2 = (const ulonglong2*)tile;
    #pragma unroll 8
    for (int i = s0; i < s1; ++i){
        ulonglong2 p = tile2[i];                // broadcast within segment waves
        rank += (p.x > mine) ? 1 : 0;
        rank += (p.y > mine) ? 1 : 0;
    }
    if (validE && rank < PRE_K){
        float4 bx = cboxes[img * CAND_CAP + e];   // slot == e: coalesced gather
        float s   = cscores[img * CAND_CAP + e];
        boxes_s[img * ROWS + rank] = bx;
        scores_s[img * ROWS + rank] = fabsf(s);
        if (s < 0.0f) atomicOr(&rminit[img * RWORDS + (rank >> 5)], 1u << (rank & 31));
    }
}

// ---- build upper-triangle IoU>thresh bitmask rows + transposed diag blocks ----
// k_diag merged (no fence needed: uses this block's own LDS staging). Waves
// gw<32 also emit colT for their 64x64 diagonal block. Staging covers ROWS;
// garbage rows >=2000 only touch bits k_scan pre-masks as removed.
__global__ __launch_bounds__(1024) void k_mask(const float4* __restrict__ boxes_s,
                                               uint32_t* __restrict__ mask,
                                               unsigned long long* __restrict__ colT){
    int img = blockIdx.x >> 4;                 // 16 blocks per image
    int rc  = blockIdx.x & 15;
    int tid = threadIdx.x;
    int lane = tid & 63;
    int wv = tid >> 6;                         // 16 waves per block
    int gw = rc * 16 + wv;                     // 0..255 wave slot within image
    __shared__ float4 B[ROWS];
    __shared__ float  AR[ROWS];
    const float4* bp = boxes_s + img * ROWS;
    for (int t = tid; t < ROWS; t += 1024){
        float4 b = bp[t]; B[t] = b;
        AR[t] = (b.z - b.x + 1.0f) * (b.w - b.y + 1.0f);
    }
    __syncthreads();
    if (gw < 32){                              // diag block gw: lane = column j
        int j = lane;
        float4 bj = B[gw * 64 + j]; float aj = AR[gw * 64 + j];
        unsigned long long col = 0ull;
        #pragma unroll 8
        for (int i = 0; i < 64; ++i){
            float4 bi = B[gw * 64 + i]; float ai = AR[gw * 64 + i];
            float xx1 = fmaxf(bi.x, bj.x), yy1 = fmaxf(bi.y, bj.y);
            float xx2 = fminf(bi.z, bj.z), yy2 = fminf(bi.w, bj.w);
            float iw = fmaxf(xx2 - xx1 + 1.0f, 0.0f);
            float ih = fmaxf(yy2 - yy1 + 1.0f, 0.0f);
            float inter = iw * ih;
            bool pred = (i < j) && (inter > NMS_TH * (ai + aj - inter));
            col |= pred ? (1ull << i) : 0ull;
        }
        colT[(size_t)(img * 32 + gw) * 64 + j] = col;
    }
    uint32_t* M = mask + (size_t)img * ROWS * RWORDS;
    for (int i = gw; i < PRE_K; i += 256){
        float4 bi = B[i];                      // same address across wave: broadcast
        float ai = AR[i];
        unsigned long long* Mrow = (unsigned long long*)(M + (size_t)i * RWORDS);
        for (int jb = (i >> 6); jb < 32; ++jb){
            int j = (jb << 6) + lane;
            bool pred = false;
            if (j > i && j < PRE_K){
                float4 bj = B[j];
                float xx1 = fmaxf(bi.x, bj.x), yy1 = fmaxf(bi.y, bj.y);
                float xx2 = fminf(bi.z, bj.z), yy2 = fminf(bi.w, bj.w);
                float iw = fmaxf(xx2 - xx1 + 1.0f, 0.0f);
                float ih = fmaxf(yy2 - yy1 + 1.0f, 0.0f);
                float inter = iw * ih;
                pred = inter > NMS_TH * (ai + AR[j] - inter);
            }
            unsigned long long bm = __ballot(pred);
            if (lane == 0) Mrow[jb] = bm;
        }
    }
}

// ---- blocked greedy NMS scan, 4-wave distributed apply + direct output ----
__global__ __launch_bounds__(256) void k_scan(const uint32_t* __restrict__ mask,
                                              const unsigned long long* __restrict__ colT,
                                              const uint32_t* __restrict__ rminit,
                                              const float4* __restrict__ boxes_s,
                                              const float* __restrict__ scores_s,
                                              float* __restrict__ out){
    int img = blockIdx.x;
    int tid = threadIdx.x;
    int lane = tid & 63;
    int wv = tid >> 6;
    const uint32_t* M = mask + (size_t)img * ROWS * RWORDS;
    const unsigned long long* CT = colT + (size_t)img * 32 * 64;
    __shared__ uint32_t S[POST_K];
    __shared__ uint32_t acc_lds[4][64];
    __shared__ unsigned long long keep_lds;

    uint32_t rm = 0u;
    if (wv == 0){
        rm = rminit[img * RWORDS + lane];
        if (lane == 62) rm |= 0xFFFF0000u;      // boxes 2000..2015
        if (lane == 63) rm  = 0xFFFFFFFFu;      // boxes 2016..2047
    }
    unsigned long long colA = 0ull, colB = 0ull, rmb_sav = 0ull;
    uint32_t rowsA[16], rowsB[16];

#define PRELOAD(B, ROWSX)                                                       \
    {                                                                           \
        const uint32_t* Mb = M + (size_t)((B) * 64 + wv * 16) * RWORDS + lane;  \
        _Pragma("unroll")                                                       \
        for (int r = 0; r < 16; ++r) ROWSX[r] = Mb[(size_t)r * RWORDS];         \
    }
#define FIXED_POINT(B, COLX)                                                    \
    {                                                                           \
        uint32_t lo = __shfl(rm, 2 * (B)), hi = __shfl(rm, 2 * (B) + 1);        \
        unsigned long long inc = ((unsigned long long)hi << 32)                 \
                               | (unsigned long long)lo;                        \
        bool alivej = ((inc >> lane) & 1ull) == 0ull;                           \
        unsigned long long keep = ~inc;                                         \
        for (int it = 0; it < 66; ++it){                                        \
            bool ok = alivej && ((COLX & keep) == 0ull);                        \
            unsigned long long nk = __ballot(ok);                              \
            if (nk == keep) break;                                              \
            keep = nk;                                                          \
        }                                                                       \
        if (lane == 0) keep_lds = keep;                                         \
        rmb_sav = ~keep;                                                        \
    }
#define APPLY(ROWSX)                                                            \
    {                                                                           \
        unsigned long long kp = keep_lds;                                       \
        uint32_t acc = 0u;                                                      \
        _Pragma("unroll")                                                       \
        for (int r = 0; r < 16; ++r)                                            \
            acc |= ((kp >> (wv * 16 + r)) & 1ull) ? ROWSX[r] : 0u;              \
        acc_lds[wv][lane] = acc;                                                \
    }
#define FINISH(B)                                                               \
    {                                                                           \
        uint32_t acc = acc_lds[0][lane] | acc_lds[1][lane]                      \
                     | acc_lds[2][lane] | acc_lds[3][lane];                     \
        rm |= (lane >= 2 * (B)) ? acc : 0u;                                     \
        if (lane == 2 * (B))     rm = (uint32_t)rmb_sav;                        \
        if (lane == 2 * (B) + 1) rm = (uint32_t)(rmb_sav >> 32);                \
    }

    // prologue: block 0 rows + col
    PRELOAD(0, rowsA);
    if (wv == 0) colA = CT[lane];

    #pragma unroll 1
    for (int b = 0; b < 32; b += 2){
        PRELOAD(b + 1, rowsB);
        if (wv == 0){
            colB = CT[(size_t)(b + 1) * 64 + lane];
            FIXED_POINT(b, colA);
        }
        __syncthreads();                        // keep_lds visible
        APPLY(rowsA);
        __syncthreads();                        // acc_lds visible
        if (wv == 0) FINISH(b);
        if (b + 2 < 32){
            PRELOAD(b + 2, rowsA);
            if (wv == 0) colA = CT[(size_t)(b + 2) * 64 + lane];
        }
        if (wv == 0) FIXED_POINT(b + 1, colB);
        __syncthreads();
        APPLY(rowsB);
        __syncthreads();
        if (wv == 0) FINISH(b + 1);
    }
#undef PRELOAD
#undef FIXED_POINT
#undef APPLY
#undef FINISH

    if (wv == 0){
        // kept = ~removed within [0, PRE_K)
        uint32_t inr = (lane < 62) ? 0xFFFFFFFFu : (lane == 62 ? 0x0000FFFFu : 0u);
        uint32_t kw = (~rm) & inr;
        uint32_t sw = rm & inr;
        uint32_t kc = __popc(kw);
        uint32_t x = kc;
        for (int d = 1; d < 64; d <<= 1){ uint32_t y = __shfl_up(x, d); if (lane >= d) x += y; }
        uint32_t kexcl = x - kc;
        uint32_t ktot = __shfl(x, 63);
        uint32_t m = kw; uint32_t r = 0;
        while (m){
            int bb = __ffs(m) - 1;
            uint32_t slot = kexcl + r;
            if (slot < POST_K) S[slot] = (uint32_t)(lane * 32 + bb) | 0x80000000u;
            m &= m - 1; ++r;
        }
        if (ktot < POST_K){   // pad with suppressed positions in index order
            uint32_t sc2 = __popc(sw);
            uint32_t x2 = sc2;
            for (int d = 1; d < 64; d <<= 1){ uint32_t y = __shfl_up(x2, d); if (lane >= d) x2 += y; }
            uint32_t sexcl = x2 - sc2;
            uint32_t m2 = sw; uint32_t r2 = 0;
            while (m2){
                int bb = __ffs(m2) - 1;
                uint32_t slot = ktot + sexcl + r2;
                if (slot >= ktot && slot < POST_K) S[slot] = (uint32_t)(lane * 32 + bb);
                m2 &= m2 - 1; ++r2;
            }
        }
    }
    __syncthreads();
    // direct output write: [1000, 5] rows for this image, 256 threads
    const float4* bp = boxes_s + img * ROWS;
    const float* sp = scores_s + img * ROWS;
    float* o = out + (size_t)img * POST_K * 5;
    for (int s = tid; s < POST_K; s += 256){
        uint32_t v = S[s];
        uint32_t pos = v & 0x7FFFFFFFu;
        bool kept = (v >> 31) != 0;
        float4 bx = bp[pos];
        float sc = kept ? sp[pos] : NEGV;
        float* oo = o + s * 5;
        oo[0] = bx.x; oo[1] = bx.y; oo[2] = bx.z; oo[3] = bx.w; oo[4] = sc;
    }
}

extern "C" void kernel_launch(void* const* d_in, const int* in_sizes, int n_in,
                              void* d_out, int out_size, void* d_ws, size_t ws_size,
                              hipStream_t stream) {
    const float* anchors = (const float*)d_in[0];
    const float* obj     = (const float*)d_in[1];
    const float* breg    = (const float*)d_in[2];
    const int*   pimh    = (const int*)d_in[3];
    const int*   pimw    = (const int*)d_in[4];
    float* out = (float*)d_out;
    uint8_t* ws = (uint8_t*)d_ws;

    uint32_t*           part     = (uint32_t*)(ws + WS_HIST);
    unsigned long long* colT     = (unsigned long long*)(ws + WS_COLT);  // alias, post-binsel
    float4*             cboxes   = (float4*)(ws + WS_CBOX);              // alias, post-binsel
    float*              cscores  = (float*)(ws + WS_CSCO);               // alias, post-binsel
    uint32_t*           cut      = (uint32_t*)(ws + WS_CUT);
    uint32_t*           nAarr    = (uint32_t*)(ws + WS_CUT + 64);
    uint32_t*           cnt      = (uint32_t*)(ws + WS_CNT);             // cntA[16], cntB[16]
    unsigned long long* cand     = (unsigned long long*)(ws + WS_CAND);
    float4*             boxes_s  = (float4*)(ws + WS_BOX);
    float*              scores_s = (float*)(ws + WS_SCO);
    uint32_t*           rminit   = (uint32_t*)(ws + WS_RMI);
    uint32_t*           mask     = (uint32_t*)(ws + WS_MASK);

    k_hist<<<NIMG * HPARTS, 1024, 0, stream>>>(obj, part, cnt, rminit);
    k_binsel<<<NIMG, 1024, 0, stream>>>(part, cut, nAarr);
    k_compact<<<NIMG * CBLOCKS, 256, 0, stream>>>(obj, cut, nAarr, cnt, cand,
                                                  anchors, breg, pimh, pimw,
                                                  cboxes, cscores);
    k_rank<<<NIMG * 16, 256, 0, stream>>>(cand, cnt, nAarr, cboxes, cscores,
                                          boxes_s, scores_s, rminit);
    k_mask<<<NIMG * 16, 1024, 0, stream>>>(boxes_s, mask, colT);
    k_scan<<<NIMG, 256, 0, stream>>>(mask, colT, rminit, boxes_s, scores_s, out);
}

// Round 20
// 132.743 us; speedup vs baseline: 1.6994x; 1.0456x over previous
//
#include <hip/hip_runtime.h>
#include <stdint.h>

// ---- problem constants (from setup_inputs) ----
#define NIMG 16
#define AANCH 3
#define HH 256
#define WW 336
#define HWP (HH*WW)            // 86016
#define NUM (AANCH*HWP)        // 258048 anchors per image
#define TOTAL (NIMG*NUM)       // 4128768
#define PRE_K 2000
#define POST_K 1000
#define NMS_TH 0.7f
#define NEGV -1e30f
#define CAND_CAP 4096
#define ROWS 2048              // padded row count for top-2000 arrays
#define RWORDS 64              // 32-bit mask words per NMS row (64*32 = 2048 bits)
#define CHUNK 4096             // elements per k_compact block
#define CBLOCKS (NUM / CHUNK)  // 63 blocks per image
#define HPARTS 16              // histogram partials per image
#define HBINS 4096             // 12-bit key prefix bins
#define HCHUNK (NUM / HPARTS)  // 16128 elements per hist block

// ---- workspace layout (bytes) ----
#define WS_HIST 0u             // 16 * 16 * 4096 * 4  = 4194304 (partial histograms)
                               // region is DEAD after k_binsel; aliased below:
#define WS_COLT 0u             //   colT   16*32*64*8 = 262144   (written by k_mask)
#define WS_CBOX 262144u        //   cboxes 16*4096*16 = 1048576  (written by k_compact)
#define WS_CSCO 1310720u       //   cscores 16*4096*4 = 262144   (written by k_compact)
#define WS_CUT  4194304u       // 16 u32 cut keys; +64B: 16 u32 nA (count above cut bin)
#define WS_CNT  4194560u       // 16 u32 cntA; 16 u32 cntB
#define WS_CAND 4194816u       // 16 * 4096 * 8       = 524288
#define WS_BOX  4719104u       // 16 * 2048 * 16      = 524288
#define WS_SCO  5243392u       // 16 * 2048 * 4       = 131072
#define WS_RMI  5374464u       // 16 * 64 * 4         = 4096
#define WS_MASK 5444096u       // 16 * 2048 * 64 * 4  = 8388608
// total ~13.8 MB

// monotonic float -> uint key (descending float == descending key)
__device__ __forceinline__ uint32_t fkey(float f){
    uint32_t b = __float_as_uint(f);
    return (b & 0x80000000u) ? ~b : (b | 0x80000000u);
}
__device__ __forceinline__ float keyf(uint32_t k){
    uint32_t b = (k & 0x80000000u) ? (k & 0x7FFFFFFFu) : ~k;
    return __uint_as_float(b);
}

// ---- per-block private LDS histogram -> global partials (no global atomics) ----
// Also zeroes cntA/cntB + rminit (block 0). NOTE: cross-XCD reduction lives in
// the separate k_binsel launch — fusing it here requires __threadfence(), which
// forces L2 writeback across 8 non-coherent XCDs and cost ~95us (R17 lesson).
__global__ __launch_bounds__(1024) void k_hist(const float* __restrict__ obj,
                                               uint32_t* __restrict__ part,
                                               uint32_t* __restrict__ cnt,
                                               uint32_t* __restrict__ rminit){
    int img = blockIdx.x >> 4;
    int blk = blockIdx.x & 15;
    int tid = threadIdx.x;
    if (blockIdx.x == 0){
        for (int i = tid; i < 32 + NIMG * RWORDS; i += 1024){
            if (i < 32) cnt[i] = 0u;             // cntA[16] + cntB[16]
            else        rminit[i - 32] = 0u;
        }
    }
    __shared__ uint32_t h[HBINS];
    #pragma unroll
    for (int i = 0; i < HBINS / 1024; ++i) h[tid + i * 1024] = 0u;
    __syncthreads();
    const float* base = obj + (size_t)img * NUM + (size_t)blk * HCHUNK;
    for (int e = tid * 4; e < HCHUNK; e += 4096){
        float4 v = *(const float4*)(base + e);
        atomicAdd(&h[fkey(v.x) >> 20], 1u);
        atomicAdd(&h[fkey(v.y) >> 20], 1u);
        atomicAdd(&h[fkey(v.z) >> 20], 1u);
        atomicAdd(&h[fkey(v.w) >> 20], 1u);
    }
    __syncthreads();
    uint32_t* p = part + ((size_t)blockIdx.x) * HBINS;
    #pragma unroll
    for (int i = 0; i < HBINS / 1024; ++i) p[tid + i * 1024] = h[tid + i * 1024];
}

// ---- merge partials, find crossing bin; emit cut key AND nA (count above bin) ----
__global__ __launch_bounds__(1024) void k_binsel(const uint32_t* __restrict__ part,
                                                 uint32_t* __restrict__ cut,
                                                 uint32_t* __restrict__ nAout){
    int img = blockIdx.x, tid = threadIdx.x;
    const uint32_t* pb = part + (size_t)img * HPARTS * HBINS;
    int bin0 = HBINS - 4 * (tid + 1);           // tid=0 covers the top 4 bins
    uint32_t c0 = 0, c1 = 0, c2 = 0, c3 = 0;
    for (int k = 0; k < HPARTS; ++k){
        const uint4 v = *(const uint4*)(pb + (size_t)k * HBINS + bin0);
        c0 += v.x; c1 += v.y; c2 += v.z; c3 += v.w;
    }
    uint32_t s = c0 + c1 + c2 + c3;
    __shared__ uint32_t ss[1024];
    uint32_t x = s;
    ss[tid] = x; __syncthreads();
    for (int d = 1; d < 1024; d <<= 1){
        uint32_t y = (tid >= d) ? ss[tid - d] : 0u;
        __syncthreads();
        x += y; ss[tid] = x;
        __syncthreads();
    }
    uint32_t incl = x, excl = x - s;
    if (excl < PRE_K && incl >= PRE_K){
        uint32_t c = excl;
        uint32_t cc[4] = {c0, c1, c2, c3};
        for (int j = 3; j >= 0; --j){            // walk bins descending by value
            uint32_t cb = c;                     // count strictly above bin (bin0+j)
            c += cc[j];
            if (c >= PRE_K){
                cut[img] = ((uint32_t)(bin0 + j)) << 20;
                nAout[img] = cb;
                break;
            }
        }
    }
}

// decode helper: composite write + box decode + clip + score
__device__ __forceinline__ void emit_candidate(
        uint32_t key, uint32_t f, uint32_t pos, int img,
        const float* __restrict__ anchors, const float* __restrict__ breg,
        float imw, float imh,
        unsigned long long* __restrict__ cand,
        float4* __restrict__ cboxes, float* __restrict__ cscores){
    const float CLIPV = 4.135166556742356f;     // log(1000/16)
    // composite: [key:32][~f:18][slot:14] — order by (key desc, f asc); f unique
    cand[img * CAND_CAP + pos] = ((unsigned long long)key << 32)
        | ((unsigned long long)((~f) & 0x3FFFFu) << 14) | (unsigned long long)pos;
    float logit = keyf(key);
    float sc = 1.0f / (1.0f + expf(-logit));
    const float* an = anchors + ((size_t)img * NUM + f) * 4;
    float ax1 = an[0], ay1 = an[1], ax2 = an[2], ay2 = an[3];
    int a = (int)(f % AANCH); int hw = (int)(f / AANCH);
    size_t bbase = ((size_t)img * 12 + a * 4) * HWP + (size_t)hw;
    float dx = breg[bbase], dy = breg[bbase + HWP];
    float dw = breg[bbase + 2 * (size_t)HWP], dh = breg[bbase + 3 * (size_t)HWP];
    float aw = ax2 - ax1 + 1.0f, ah = ay2 - ay1 + 1.0f;
    float cx = ax1 + 0.5f * aw, cy = ay1 + 0.5f * ah;
    dw = fminf(dw, CLIPV); dh = fminf(dh, CLIPV);
    float pcx = dx * aw + cx, pcy = dy * ah + cy;
    float pw = expf(dw) * aw, ph = expf(dh) * ah;
    float x1 = pcx - 0.5f * pw, y1 = pcy - 0.5f * ph;
    float x2 = pcx + 0.5f * pw - 1.0f, y2 = pcy + 0.5f * ph - 1.0f;
    x1 = fminf(fmaxf(x1, 0.0f), imw - 1.0f);
    y1 = fminf(fmaxf(y1, 0.0f), imh - 1.0f);
    x2 = fminf(fmaxf(x2, 0.0f), imw - 1.0f);
    y2 = fminf(fmaxf(y2, 0.0f), imh - 1.0f);
    bool valid = ((x2 - x1 + 1.0f) >= 0.0f) && ((y2 - y1 + 1.0f) >= 0.0f);
    cboxes[img * CAND_CAP + pos] = make_float4(x1, y1, x2, y2);
    cscores[img * CAND_CAP + pos] = valid ? sc : -sc;   // sign bit = validity
}

// ---- compact into TWO segments: A (bins > cutbin) at [0,nA), B (cut bin) at [nAp,..) ----
__global__ __launch_bounds__(256) void k_compact(const float* __restrict__ obj,
                                                 const uint32_t* __restrict__ cut,
                                                 const uint32_t* __restrict__ nAarr,
                                                 uint32_t* __restrict__ cnt,
                                                 unsigned long long* __restrict__ cand,
                                                 const float* __restrict__ anchors,
                                                 const float* __restrict__ breg,
                                                 const int* __restrict__ pimh,
                                                 const int* __restrict__ pimw,
                                                 float4* __restrict__ cboxes,
                                                 float* __restrict__ cscores){
    int img   = blockIdx.x / CBLOCKS;
    int chunk = blockIdx.x - img * CBLOCKS;
    int base  = img * NUM + chunk * CHUNK;     // flat element base
    __shared__ uint32_t lcA, lcB, gbA, gbB;
    __shared__ uint2 lbuf[CHUNK];              // A from front, B from back (32 KB)
    if (threadIdx.x == 0){ lcA = 0u; lcB = 0u; }
    __syncthreads();
    uint32_t cutv = cut[img];
    uint32_t cutbin = cutv >> 20;
    float4 v[4];
    #pragma unroll
    for (int it = 0; it < 4; ++it)             // 4 independent loads in flight
        v[it] = *(const float4*)(obj + base + it * 1024 + (int)threadIdx.x * 4);
    #pragma unroll
    for (int it = 0; it < 4; ++it){
        int e = it * 1024 + (int)threadIdx.x * 4;
        float vv[4] = {v[it].x, v[it].y, v[it].z, v[it].w};
        #pragma unroll
        for (int q = 0; q < 4; ++q){
            uint32_t k = fkey(vv[q]);
            if (k >= cutv){
                int r = chunk * CHUNK + e + q;       // index within image (a,h,w flat)
                int a = r / HWP, hw = r - a * HWP;
                uint32_t f = (uint32_t)(hw * AANCH + a);  // permute_and_flatten index
                if ((k >> 20) > cutbin){
                    uint32_t p = atomicAdd(&lcA, 1u);
                    lbuf[p] = make_uint2(k, f);
                } else {
                    uint32_t p = atomicAdd(&lcB, 1u);
                    lbuf[CHUNK - 1 - p] = make_uint2(k, f);
                }
            }
        }
    }
    __syncthreads();
    if (threadIdx.x == 0){
        gbA = (lcA > 0u) ? atomicAdd(&cnt[img], lcA) : 0u;
        gbB = (lcB > 0u) ? atomicAdd(&cnt[16 + img], lcB) : 0u;
    }
    __syncthreads();
    uint32_t nA  = nAarr[img];
    uint32_t nAp = (nA + 1u) & ~1u;
    float imw = (float)(*pimw), imh = (float)(*pimh);
    uint32_t na = lcA, ga = gbA, nb = lcB, gb = gbB;
    for (uint32_t t = threadIdx.x; t < na; t += 256u){
        uint32_t pos = ga + t;                  // pos < nA <= CAND_CAP guaranteed
        uint2 kf = lbuf[t];
        emit_candidate(kf.x, kf.y, pos, img, anchors, breg, imw, imh,
                       cand, cboxes, cscores);
    }
    for (uint32_t t = threadIdx.x; t < nb; t += 256u){
        uint32_t pos = nAp + gb + t;
        if (pos < CAND_CAP){
            uint2 kf = lbuf[CHUNK - 1 - t];
            emit_candidate(kf.x, kf.y, pos, img, anchors, breg, imw, imh,
                           cand, cboxes, cscores);
        }
    }
}

// ---- segmented O(n^2) rank: A scans A only, B scans B only (rank base = nA) ----
__global__ __launch_bounds__(256) void k_rank(
        const unsigned long long* __restrict__ cand, const uint32_t* __restrict__ cnt,
        const uint32_t* __restrict__ nAarr,
        const float4* __restrict__ cboxes, const float* __restrict__ cscores,
        float4* __restrict__ boxes_s, float* __restrict__ scores_s,
        uint32_t* __restrict__ rminit){
    int img = blockIdx.x >> 4;
    int b   = blockIdx.x & 15;
    int tid = threadIdx.x;
    int e   = b * 256 + tid;
    uint32_t nA   = nAarr[img];
    uint32_t nAp  = (nA + 1u) & ~1u;
    uint32_t nB   = min(cnt[16 + img], (uint32_t)CAND_CAP - nAp);
    uint32_t end  = nAp + nB;
    uint32_t endp = (end + 1u) & ~1u;
    const unsigned long long* cp = cand + img * CAND_CAP;
    __shared__ alignas(16) unsigned long long tile[CAND_CAP];
    for (int i = tid; i < (int)endp; i += 256){
        bool v = (i < (int)nA) || (i >= (int)nAp && i < (int)end);
        tile[i] = v ? cp[i] : 0ull;             // zero fillers never outrank
    }
    __syncthreads();
    bool inA = e < (int)nA;
    bool inB = (e >= (int)nAp) && (e < (int)end);
    bool validE = inA || inB;
    unsigned long long mine = validE ? tile[e] : ~0ull;
    int s0 = inA ? 0 : (inB ? (int)(nAp >> 1) : 0);
    int s1 = inA ? (int)(nAp >> 1) : (inB ? (int)(endp >> 1) : 0);
    int rank = inB ? (int)nA : 0;
    const ulonglong2* tile2 = (const ulonglong2*)tile;
    #pragma unroll 8
    for (int i = s0; i < s1; ++i){
        ulonglong2 p = tile2[i];                // broadcast within segment waves
        rank += (p.x > mine) ? 1 : 0;
        rank += (p.y > mine) ? 1 : 0;
    }
    if (validE && rank < PRE_K){
        float4 bx = cboxes[img * CAND_CAP + e];   // slot == e: coalesced gather
        float s   = cscores[img * CAND_CAP + e];
        boxes_s[img * ROWS + rank] = bx;
        scores_s[img * ROWS + rank] = fabsf(s);
        if (s < 0.0f) atomicOr(&rminit[img * RWORDS + (rank >> 5)], 1u << (rank & 31));
    }
}

// ---- build upper-triangle IoU>thresh bitmask rows + transposed diag blocks ----
// 512 threads x 32 blocks/image: 40KB LDS x 4 blocks/CU = 160KB exactly ->
// 32 waves/CU (2x latency hiding vs 1024-thread config). Inner loop split:
// diagonal block (j>i check), clean middle (no predicates), tail jb=31
// (j<PRE_K check). IoU predicate arithmetic is UNCHANGED (bit-exact pass).
__global__ __launch_bounds__(512) void k_mask(const float4* __restrict__ boxes_s,
                                              uint32_t* __restrict__ mask,
                                              unsigned long long* __restrict__ colT){
    int img = blockIdx.x >> 5;                 // 32 blocks per image
    int rc  = blockIdx.x & 31;
    int tid = threadIdx.x;
    int lane = tid & 63;
    int wv = tid >> 6;                         // 8 waves per block
    int gw = rc * 8 + wv;                      // 0..255 wave slot within image
    __shared__ float4 B[ROWS];
    __shared__ float  AR[ROWS];
    const float4* bp = boxes_s + img * ROWS;
    for (int t = tid; t < ROWS; t += 512){
        float4 b = bp[t]; B[t] = b;
        AR[t] = (b.z - b.x + 1.0f) * (b.w - b.y + 1.0f);
    }
    __syncthreads();
    if (gw < 32){                              // diag block gw: lane = column j
        int j = lane;
        float4 bj = B[gw * 64 + j]; float aj = AR[gw * 64 + j];
        unsigned long long col = 0ull;
        #pragma unroll 8
        for (int i = 0; i < 64; ++i){
            float4 bi = B[gw * 64 + i]; float ai = AR[gw * 64 + i];
            float xx1 = fmaxf(bi.x, bj.x), yy1 = fmaxf(bi.y, bj.y);
            float xx2 = fminf(bi.z, bj.z), yy2 = fminf(bi.w, bj.w);
            float iw = fmaxf(xx2 - xx1 + 1.0f, 0.0f);
            float ih = fmaxf(yy2 - yy1 + 1.0f, 0.0f);
            float inter = iw * ih;
            bool pred = (i < j) && (inter > NMS_TH * (ai + aj - inter));
            col |= pred ? (1ull << i) : 0ull;
        }
        colT[(size_t)(img * 32 + gw) * 64 + j] = col;
    }
    uint32_t* M = mask + (size_t)img * ROWS * RWORDS;
#define IOU_PRED(BI, AI, BJ, AJ, OUT)                                           \
    {                                                                           \
        float xx1 = fmaxf((BI).x, (BJ).x), yy1 = fmaxf((BI).y, (BJ).y);         \
        float xx2 = fminf((BI).z, (BJ).z), yy2 = fminf((BI).w, (BJ).w);         \
        float iw = fmaxf(xx2 - xx1 + 1.0f, 0.0f);                               \
        float ih = fmaxf(yy2 - yy1 + 1.0f, 0.0f);                               \
        float inter = iw * ih;                                                  \
        OUT = inter > NMS_TH * ((AI) + (AJ) - inter);                           \
    }
    for (int i = gw; i < PRE_K; i += 256){
        float4 bi = B[i];                      // same address across wave: broadcast
        float ai = AR[i];
        unsigned long long* Mrow = (unsigned long long*)(M + (size_t)i * RWORDS);
        int jb0 = i >> 6;
        {   // diagonal block: needs j>i (and j<PRE_K when jb0==31)
            int j = (jb0 << 6) + lane;
            bool pred = false;
            if (j > i && j < PRE_K){
                float4 bj = B[j];
                IOU_PRED(bi, ai, bj, AR[j], pred);
            }
            unsigned long long bm = __ballot(pred);
            if (lane == 0) Mrow[jb0] = bm;
        }
        #pragma unroll 2
        for (int jb = jb0 + 1; jb < 31; ++jb){ // clean middle: j>i, j<2000 proven
            int j = (jb << 6) + lane;
            float4 bj = B[j];
            bool pred;
            IOU_PRED(bi, ai, bj, AR[j], pred);
            unsigned long long bm = __ballot(pred);
            if (lane == 0) Mrow[jb] = bm;
        }
        if (jb0 < 31){                         // tail block 31: j<PRE_K check only
            int j = (31 << 6) + lane;
            bool pred = false;
            if (j < PRE_K){
                float4 bj = B[j];
                IOU_PRED(bi, ai, bj, AR[j], pred);
            }
            unsigned long long bm = __ballot(pred);
            if (lane == 0) Mrow[31] = bm;
        }
    }
#undef IOU_PRED
}

// ---- blocked greedy NMS scan, 4-wave distributed apply + direct output ----
__global__ __launch_bounds__(256) void k_scan(const uint32_t* __restrict__ mask,
                                              const unsigned long long* __restrict__ colT,
                                              const uint32_t* __restrict__ rminit,
                                              const float4* __restrict__ boxes_s,
                                              const float* __restrict__ scores_s,
                                              float* __restrict__ out){
    int img = blockIdx.x;
    int tid = threadIdx.x;
    int lane = tid & 63;
    int wv = tid >> 6;
    const uint32_t* M = mask + (size_t)img * ROWS * RWORDS;
    const unsigned long long* CT = colT + (size_t)img * 32 * 64;
    __shared__ uint32_t S[POST_K];
    __shared__ uint32_t acc_lds[4][64];
    __shared__ unsigned long long keep_lds;

    uint32_t rm = 0u;
    if (wv == 0){
        rm = rminit[img * RWORDS + lane];
        if (lane == 62) rm |= 0xFFFF0000u;      // boxes 2000..2015
        if (lane == 63) rm  = 0xFFFFFFFFu;      // boxes 2016..2047
    }
    unsigned long long colA = 0ull, colB = 0ull, rmb_sav = 0ull;
    uint32_t rowsA[16], rowsB[16];

#define PRELOAD(B, ROWSX)                                                       \
    {                                                                           \
        const uint32_t* Mb = M + (size_t)((B) * 64 + wv * 16) * RWORDS + lane;  \
        _Pragma("unroll")                                                       \
        for (int r = 0; r < 16; ++r) ROWSX[r] = Mb[(size_t)r * RWORDS];         \
    }
#define FIXED_POINT(B, COLX)                                                    \
    {                                                                           \
        uint32_t lo = __shfl(rm, 2 * (B)), hi = __shfl(rm, 2 * (B) + 1);        \
        unsigned long long inc = ((unsigned long long)hi << 32)                 \
                               | (unsigned long long)lo;                        \
        bool alivej = ((inc >> lane) & 1ull) == 0ull;                           \
        unsigned long long keep = ~inc;                                         \
        for (int it = 0; it < 66; ++it){                                        \
            bool ok = alivej && ((COLX & keep) == 0ull);                        \
            unsigned long long nk = __ballot(ok);                              \
            if (nk == keep) break;                                              \
            keep = nk;                                                          \
        }                                                                       \
        if (lane == 0) keep_lds = keep;                                         \
        rmb_sav = ~keep;                                                        \
    }
#define APPLY(ROWSX)                                                            \
    {                                                                           \
        unsigned long long kp = keep_lds;                                       \
        uint32_t acc = 0u;                                                      \
        _Pragma("unroll")                                                       \
        for (int r = 0; r < 16; ++r)                                            \
            acc |= ((kp >> (wv * 16 + r)) & 1ull) ? ROWSX[r] : 0u;              \
        acc_lds[wv][lane] = acc;                                                \
    }
#define FINISH(B)                                                               \
    {                                                                           \
        uint32_t acc = acc_lds[0][lane] | acc_lds[1][lane]                      \
                     | acc_lds[2][lane] | acc_lds[3][lane];                     \
        rm |= (lane >= 2 * (B)) ? acc : 0u;                                     \
        if (lane == 2 * (B))     rm = (uint32_t)rmb_sav;                        \
        if (lane == 2 * (B) + 1) rm = (uint32_t)(rmb_sav >> 32);                \
    }

    // prologue: block 0 rows + col
    PRELOAD(0, rowsA);
    if (wv == 0) colA = CT[lane];

    #pragma unroll 1
    for (int b = 0; b < 32; b += 2){
        PRELOAD(b + 1, rowsB);
        if (wv == 0){
            colB = CT[(size_t)(b + 1) * 64 + lane];
            FIXED_POINT(b, colA);
        }
        __syncthreads();                        // keep_lds visible
        APPLY(rowsA);
        __syncthreads();                        // acc_lds visible
        if (wv == 0) FINISH(b);
        if (b + 2 < 32){
            PRELOAD(b + 2, rowsA);
            if (wv == 0) colA = CT[(size_t)(b + 2) * 64 + lane];
        }
        if (wv == 0) FIXED_POINT(b + 1, colB);
        __syncthreads();
        APPLY(rowsB);
        __syncthreads();
        if (wv == 0) FINISH(b + 1);
    }
#undef PRELOAD
#undef FIXED_POINT
#undef APPLY
#undef FINISH

    if (wv == 0){
        // kept = ~removed within [0, PRE_K)
        uint32_t inr = (lane < 62) ? 0xFFFFFFFFu : (lane == 62 ? 0x0000FFFFu : 0u);
        uint32_t kw = (~rm) & inr;
        uint32_t sw = rm & inr;
        uint32_t kc = __popc(kw);
        uint32_t x = kc;
        for (int d = 1; d < 64; d <<= 1){ uint32_t y = __shfl_up(x, d); if (lane >= d) x += y; }
        uint32_t kexcl = x - kc;
        uint32_t ktot = __shfl(x, 63);
        uint32_t m = kw; uint32_t r = 0;
        while (m){
            int bb = __ffs(m) - 1;
            uint32_t slot = kexcl + r;
            if (slot < POST_K) S[slot] = (uint32_t)(lane * 32 + bb) | 0x80000000u;
            m &= m - 1; ++r;
        }
        if (ktot < POST_K){   // pad with suppressed positions in index order
            uint32_t sc2 = __popc(sw);
            uint32_t x2 = sc2;
            for (int d = 1; d < 64; d <<= 1){ uint32_t y = __shfl_up(x2, d); if (lane >= d) x2 += y; }
            uint32_t sexcl = x2 - sc2;
            uint32_t m2 = sw; uint32_t r2 = 0;
            while (m2){
                int bb = __ffs(m2) - 1;
                uint32_t slot = ktot + sexcl + r2;
                if (slot >= ktot && slot < POST_K) S[slot] = (uint32_t)(lane * 32 + bb);
                m2 &= m2 - 1; ++r2;
            }
        }
    }
    __syncthreads();
    // direct output write: [1000, 5] rows for this image, 256 threads
    const float4* bp = boxes_s + img * ROWS;
    const float* sp = scores_s + img * ROWS;
    float* o = out + (size_t)img * POST_K * 5;
    for (int s = tid; s < POST_K; s += 256){
        uint32_t v = S[s];
        uint32_t pos = v & 0x7FFFFFFFu;
        bool kept = (v >> 31) != 0;
        float4 bx = bp[pos];
        float sc = kept ? sp[pos] : NEGV;
        float* oo = o + s * 5;
        oo[0] = bx.x; oo[1] = bx.y; oo[2] = bx.z; oo[3] = bx.w; oo[4] = sc;
    }
}

extern "C" void kernel_launch(void* const* d_in, const int* in_sizes, int n_in,
                              void* d_out, int out_size, void* d_ws, size_t ws_size,
                              hipStream_t stream) {
    const float* anchors = (const float*)d_in[0];
    const float* obj     = (const float*)d_in[1];
    const float* breg    = (const float*)d_in[2];
    const int*   pimh    = (const int*)d_in[3];
    const int*   pimw    = (const int*)d_in[4];
    float* out = (float*)d_out;
    uint8_t* ws = (uint8_t*)d_ws;

    uint32_t*           part     = (uint32_t*)(ws + WS_HIST);
    unsigned long long* colT     = (unsigned long long*)(ws + WS_COLT);  // alias, post-binsel
    float4*             cboxes   = (float4*)(ws + WS_CBOX);              // alias, post-binsel
    float*              cscores  = (float*)(ws + WS_CSCO);               // alias, post-binsel
    uint32_t*           cut      = (uint32_t*)(ws + WS_CUT);
    uint32_t*           nAarr    = (uint32_t*)(ws + WS_CUT + 64);
    uint32_t*           cnt      = (uint32_t*)(ws + WS_CNT);             // cntA[16], cntB[16]
    unsigned long long* cand     = (unsigned long long*)(ws + WS_CAND);
    float4*             boxes_s  = (float4*)(ws + WS_BOX);
    float*              scores_s = (float*)(ws + WS_SCO);
    uint32_t*           rminit   = (uint32_t*)(ws + WS_RMI);
    uint32_t*           mask     = (uint32_t*)(ws + WS_MASK);

    k_hist<<<NIMG * HPARTS, 1024, 0, stream>>>(obj, part, cnt, rminit);
    k_binsel<<<NIMG, 1024, 0, stream>>>(part, cut, nAarr);
    k_compact<<<NIMG * CBLOCKS, 256, 0, stream>>>(obj, cut, nAarr, cnt, cand,
                                                  anchors, breg, pimh, pimw,
                                                  cboxes, cscores);
    k_rank<<<NIMG * 16, 256, 0, stream>>>(cand, cnt, nAarr, cboxes, cscores,
                                          boxes_s, scores_s, rminit);
    k_mask<<<NIMG * 32, 512, 0, stream>>>(boxes_s, mask, colT);
    k_scan<<<NIMG, 256, 0, stream>>>(mask, colT, rminit, boxes_s, scores_s, out);
}